// Round 2
// baseline (22962.381 us; speedup 1.0000x reference)
//
#include <hip/hip_runtime.h>
#include <hip/hip_bf16.h>

#define HIDN 1024
#define LATD 128
#define INPD 512
#define BATCH 128
#define NG 4096  // 4*HIDN

typedef unsigned short u16;
typedef __attribute__((ext_vector_type(8))) short s16x8;
typedef __attribute__((ext_vector_type(4))) float f32x4;

__device__ __forceinline__ u16 f2bf(float f) {
    union { float f; unsigned u; } x;
    x.f = f;
    unsigned r = x.u + 0x7fffu + ((x.u >> 16) & 1u);
    return (u16)(r >> 16);
}
__device__ __forceinline__ float sigm(float x) {
    return 1.f / (1.f + __expf(-x));
}

// ---------------------------------------------------------------------------
// f32 -> bf16 conversion, 4 elements/thread (all sizes are multiples of 4)
// ---------------------------------------------------------------------------
__global__ __launch_bounds__(256) void k_cvt(
    const float* __restrict__ src, u16* __restrict__ dst, int n4)
{
    int i = blockIdx.x * 256 + threadIdx.x;
    if (i < n4) {
        float4 v = ((const float4*)src)[i];
        ushort4 o;
        o.x = f2bf(v.x); o.y = f2bf(v.y); o.z = f2bf(v.z); o.w = f2bf(v.w);
        ((ushort4*)dst)[i] = o;
    }
}

// ---------------------------------------------------------------------------
// init: dh = latent @ W_fc.T + b_fc  -> scatter into h[l][b][k], c[l][b][k]
// dh element (b, n): l = b>>6 ; bb = 2*(b&63) + (n>>11) ; k2 = n&2047
//   k2 <1024 -> h[l][bb][k2] ; else c[l][bb][k2-1024]
// ---------------------------------------------------------------------------
__global__ __launch_bounds__(256) void k_init(
    const u16* __restrict__ latent, const u16* __restrict__ Wfc,
    const float* __restrict__ bfc,
    u16* __restrict__ h_bf,      // parity-0: [2 layer][B][HIDN]
    u16* __restrict__ c_bf,      // [2][B][HIDN]
    float* __restrict__ c_f32)   // [2][B][HIDN]
{
    int tid = threadIdx.x, lane = tid & 63, w = tid >> 6;
    int blk = blockIdx.x;              // mt*64 + ngi
    int mt = blk >> 6, ngi = blk & 63;
    int nt = ngi * 4 + w;              // 0..255
    int arow = mt * 16 + (lane & 15);
    int ak = (lane >> 4) * 8;
    int bn = nt * 16 + (lane & 15);
    const u16* xp = latent + (size_t)arow * LATD + ak;
    const u16* wp = Wfc + (size_t)bn * LATD + ak;
    f32x4 acc = {0.f, 0.f, 0.f, 0.f};
#pragma unroll
    for (int kk = 0; kk < LATD; kk += 32) {
        s16x8 a = *(const s16x8*)(xp + kk);
        s16x8 b = *(const s16x8*)(wp + kk);
        acc = __builtin_amdgcn_mfma_f32_16x16x32_bf16(a, b, acc, 0, 0, 0);
    }
    int col = lane & 15, rbase = (lane >> 4) * 4;
    int n = nt * 16 + col;
    float bias = bfc[n];
#pragma unroll
    for (int r = 0; r < 4; ++r) {
        int m = mt * 16 + rbase + r;          // original batch row
        float v = acc[r] + bias;
        int ll = m >> 6;
        int bb = 2 * (m & 63) + (n >> 11);
        int k2 = n & 2047;
        size_t base = ((size_t)(ll * BATCH + bb)) << 10;
        if (k2 < 1024) {
            h_bf[base + k2] = f2bf(v);
        } else {
            int kq = k2 - 1024;
            c_f32[base + kq] = v;
            c_bf[base + kq] = f2bf(v);
        }
    }
}

// ---------------------------------------------------------------------------
// map: out_t = sigmoid(fc_in @ W_map.T + b_map), fc_in is the scrambled
// concat view: row i segments [h_l[2(i&63)], c_l[2(i&63)], h_l[+1], c_l[+1]],
// l = i>>6. Writes f32 to d_out and bf16 to out_bf (cell0's X).
// ---------------------------------------------------------------------------
__global__ __launch_bounds__(256) void k_map(
    const u16* __restrict__ hcur,   // [2][B][HIDN]
    const u16* __restrict__ cbf,    // [2][B][HIDN]
    const u16* __restrict__ Wmap,   // [INPD][NG] bf16
    const float* __restrict__ bmap,
    float* __restrict__ out,        // d_out + t*B*INPD (f32)
    u16* __restrict__ out_bf)       // [B][INPD] bf16
{
    int tid = threadIdx.x, lane = tid & 63, w = tid >> 6;
    int blk = blockIdx.x;            // mt*8 + ngi
    int mt = blk >> 3, ngi = blk & 7;
    int nt = ngi * 4 + w;            // 0..31
    int arow = mt * 16 + (lane & 15);
    int ak = (lane >> 4) * 8;
    int ll = arow >> 6;
    int b0 = 2 * (arow & 63);
    const u16* seg0 = hcur + (((size_t)(ll * BATCH + b0)) << 10);
    const u16* seg1 = cbf  + (((size_t)(ll * BATCH + b0)) << 10);
    const u16* seg2 = hcur + (((size_t)(ll * BATCH + b0 + 1)) << 10);
    const u16* seg3 = cbf  + (((size_t)(ll * BATCH + b0 + 1)) << 10);
    int bn = nt * 16 + (lane & 15);
    const u16* wrow = Wmap + ((size_t)bn) * NG;
    f32x4 acc = {0.f, 0.f, 0.f, 0.f};
#pragma unroll
    for (int seg = 0; seg < 4; ++seg) {
        const u16* xp = (seg == 0 ? seg0 : seg == 1 ? seg1 : seg == 2 ? seg2 : seg3) + ak;
        const u16* wp = wrow + (seg << 10) + ak;
#pragma unroll 4
        for (int kk = 0; kk < 1024; kk += 32) {
            s16x8 a = *(const s16x8*)(xp + kk);
            s16x8 b = *(const s16x8*)(wp + kk);
            acc = __builtin_amdgcn_mfma_f32_16x16x32_bf16(a, b, acc, 0, 0, 0);
        }
    }
    int col = lane & 15, rbase = (lane >> 4) * 4;
    int n = nt * 16 + col;
    float bias = bmap[n];
#pragma unroll
    for (int r = 0; r < 4; ++r) {
        int m = mt * 16 + rbase + r;
        float v = sigm(acc[r] + bias);
        out[(size_t)m * INPD + n] = v;
        out_bf[(size_t)m * INPD + n] = f2bf(v);
    }
}

// ---------------------------------------------------------------------------
// cell: gates = X @ Wih.T + hprev @ Whh.T + bih + bhh (gate order i,f,g,o)
// then c2 = sig(f)*c + sig(i)*tanh(g); h2 = sig(o)*tanh(c2)
// block = (mt, jt): 4 waves, wave w computes gate w's 16x16 tile.
// ---------------------------------------------------------------------------
__global__ __launch_bounds__(256) void k_cell(
    const u16* __restrict__ X, int Kx,
    const u16* __restrict__ Wih, const u16* __restrict__ Whh,
    const float* __restrict__ bih, const float* __restrict__ bhh,
    const u16* __restrict__ hprev,  // [B][HIDN]
    u16* __restrict__ hnew,         // [B][HIDN]
    float* __restrict__ cst,        // [B][HIDN] f32 (in-place)
    u16* __restrict__ cbf)          // [B][HIDN]
{
    __shared__ float g_lds[4][16][16];
    int tid = threadIdx.x, lane = tid & 63, w = tid >> 6;
    int blk = blockIdx.x;            // mt*64 + jt
    int mt = blk >> 6, jt = blk & 63;
    int arow = mt * 16 + (lane & 15);
    int ak = (lane >> 4) * 8;
    int nrow = (w << 10) + jt * 16 + (lane & 15);   // gate-major W row
    f32x4 acc = {0.f, 0.f, 0.f, 0.f};
    {
        const u16* xp = X + (size_t)arow * Kx + ak;
        const u16* wp = Wih + (size_t)nrow * Kx + ak;
#pragma unroll 4
        for (int kk = 0; kk < Kx; kk += 32) {
            s16x8 a = *(const s16x8*)(xp + kk);
            s16x8 b = *(const s16x8*)(wp + kk);
            acc = __builtin_amdgcn_mfma_f32_16x16x32_bf16(a, b, acc, 0, 0, 0);
        }
    }
    {
        const u16* xp = hprev + ((size_t)arow << 10) + ak;
        const u16* wp = Whh + ((size_t)nrow << 10) + ak;
#pragma unroll 4
        for (int kk = 0; kk < HIDN; kk += 32) {
            s16x8 a = *(const s16x8*)(xp + kk);
            s16x8 b = *(const s16x8*)(wp + kk);
            acc = __builtin_amdgcn_mfma_f32_16x16x32_bf16(a, b, acc, 0, 0, 0);
        }
    }
    int col = lane & 15, rbase = (lane >> 4) * 4;
    float bias = bih[nrow] + bhh[nrow];
#pragma unroll
    for (int r = 0; r < 4; ++r) g_lds[w][rbase + r][col] = acc[r] + bias;
    __syncthreads();
    int rr = tid >> 4, cc = tid & 15;
    int b = mt * 16 + rr;
    int j = jt * 16 + cc;
    float ig = g_lds[0][rr][cc];
    float fg = g_lds[1][rr][cc];
    float gg = g_lds[2][rr][cc];
    float og = g_lds[3][rr][cc];
    float i = sigm(ig);
    float f = sigm(fg);
    float g = tanhf(gg);
    float o = sigm(og);
    size_t idx = (((size_t)b) << 10) + j;
    float c2 = f * cst[idx] + i * g;
    float h2 = o * tanhf(c2);
    cst[idx] = c2;
    cbf[idx] = f2bf(c2);
    hnew[idx] = f2bf(h2);
}

extern "C" void kernel_launch(void* const* d_in, const int* in_sizes, int n_in,
                              void* d_out, int out_size, void* d_ws, size_t ws_size,
                              hipStream_t stream)
{
    const float* latent = (const float*)d_in[0];
    // d_in[1] = seq_length (int scalar); derived from out_size instead
    const float* Wfc  = (const float*)d_in[2];
    const float* bfc  = (const float*)d_in[3];
    const float* Wmap = (const float*)d_in[4];
    const float* bmap = (const float*)d_in[5];
    const float* Wih0 = (const float*)d_in[6];
    const float* Whh0 = (const float*)d_in[7];
    const float* bih0 = (const float*)d_in[8];
    const float* bhh0 = (const float*)d_in[9];
    const float* Wih1 = (const float*)d_in[10];
    const float* Whh1 = (const float*)d_in[11];
    const float* bih1 = (const float*)d_in[12];
    const float* bhh1 = (const float*)d_in[13];
    float* out = (float*)d_out;
    int seq = out_size / (BATCH * INPD);

    // ---- workspace layout (all element counts multiples of 8) ----
    const size_t N_LAT = (size_t)BATCH * LATD;        //    16384
    const size_t N_FC  = (size_t)NG * LATD;           //   524288
    const size_t N_MAP = (size_t)INPD * NG;           //  2097152
    const size_t N_IH0 = (size_t)NG * INPD;           //  2097152
    const size_t N_HH  = (size_t)NG * HIDN;           //  4194304
    const size_t LBH   = (size_t)BATCH * HIDN;        //   131072

    u16* p = (u16*)d_ws;
    u16* wbf_lat = p; p += N_LAT;
    u16* wbf_fc  = p; p += N_FC;
    u16* wbf_map = p; p += N_MAP;
    u16* wbf_ih0 = p; p += N_IH0;
    u16* wbf_hh0 = p; p += N_HH;
    u16* wbf_ih1 = p; p += N_HH;
    u16* wbf_hh1 = p; p += N_HH;
    u16* h_bf    = p; p += 4 * LBH;   // [2 parity][2 layer][B][H]
    u16* c_bf    = p; p += 2 * LBH;   // [2 layer][B][H]
    u16* out_bf  = p; p += (size_t)BATCH * INPD;
    float* c_f32 = (float*)p;         // [2 layer][B][H] f32

    // ---- weight conversion (re-done every call; weights are re-pristined) --
    {
        struct { const float* s; u16* d; size_t n; } cv[7] = {
            {latent, wbf_lat, N_LAT}, {Wfc, wbf_fc, N_FC}, {Wmap, wbf_map, N_MAP},
            {Wih0, wbf_ih0, N_IH0}, {Whh0, wbf_hh0, N_HH},
            {Wih1, wbf_ih1, N_HH}, {Whh1, wbf_hh1, N_HH}};
        for (int q = 0; q < 7; ++q) {
            int n4 = (int)(cv[q].n / 4);
            k_cvt<<<(n4 + 255) / 256, 256, 0, stream>>>(cv[q].s, cv[q].d, n4);
        }
    }

    k_init<<<512, 256, 0, stream>>>(wbf_lat, wbf_fc, bfc, h_bf, c_bf, c_f32);

    for (int t = 0; t < seq; ++t) {
        int par = t & 1;
        const u16* hcur = h_bf + (size_t)par * 2 * LBH;
        u16* hnew       = h_bf + (size_t)(par ^ 1) * 2 * LBH;
        float* ot = out + (size_t)t * BATCH * INPD;

        k_map<<<64, 256, 0, stream>>>(hcur, c_bf, wbf_map, bmap, ot, out_bf);

        k_cell<<<512, 256, 0, stream>>>(out_bf, INPD, wbf_ih0, wbf_hh0, bih0, bhh0,
                                        hcur, hnew, c_f32, c_bf);

        k_cell<<<512, 256, 0, stream>>>(hnew, HIDN, wbf_ih1, wbf_hh1, bih1, bhh1,
                                        hcur + LBH, hnew + LBH,
                                        c_f32 + LBH, c_bf + LBH);
    }
}